// Round 13
// baseline (345.253 us; speedup 1.0000x reference)
//
#include <hip/hip_runtime.h>
#include <cstdint>

#define B_SZ 1024

// ---------------------------------------------------------------------------
// Threefry-2x32 (20 rounds), exactly as jax._src.prng.threefry2x32.
// ---------------------------------------------------------------------------
__host__ __device__ inline void tf2x32(uint32_t k0, uint32_t k1,
                                       uint32_t x0, uint32_t x1,
                                       uint32_t& o0, uint32_t& o1) {
  uint32_t ks2 = 0x1BD11BDAu ^ k0 ^ k1;
#define TF_RND(r) { x0 += x1; x1 = (x1 << (r)) | (x1 >> (32 - (r))); x1 ^= x0; }
  x0 += k0; x1 += k1;
  TF_RND(13) TF_RND(15) TF_RND(26) TF_RND(6)
  x0 += k1; x1 += ks2 + 1u;
  TF_RND(17) TF_RND(29) TF_RND(16) TF_RND(24)
  x0 += ks2; x1 += k0 + 2u;
  TF_RND(13) TF_RND(15) TF_RND(26) TF_RND(6)
  x0 += k0; x1 += k1 + 3u;
  TF_RND(17) TF_RND(29) TF_RND(16) TF_RND(24)
  x0 += k1; x1 += ks2 + 4u;
  TF_RND(13) TF_RND(15) TF_RND(26) TF_RND(6)
  x0 += ks2; x1 += k0 + 5u;
#undef TF_RND
  o0 = x0; o1 = x1;
}

// XLA ErfInv f32 expansion, identical coefficients.
__device__ inline float erfinv_f32(float x) {
  float w = -log1pf(-x * x);
  float p;
  if (w < 5.0f) {
    w -= 2.5f;
    p = 2.81022636e-08f;
    p = fmaf(p, w, 3.43273939e-07f);
    p = fmaf(p, w, -3.5233877e-06f);
    p = fmaf(p, w, -4.39150654e-06f);
    p = fmaf(p, w, 0.00021858087f);
    p = fmaf(p, w, -0.00125372503f);
    p = fmaf(p, w, -0.00417768164f);
    p = fmaf(p, w, 0.246640727f);
    p = fmaf(p, w, 1.50140941f);
  } else {
    w = sqrtf(w) - 3.0f;
    p = -0.000200214257f;
    p = fmaf(p, w, 0.000100950558f);
    p = fmaf(p, w, 0.00134934322f);
    p = fmaf(p, w, -0.00367342844f);
    p = fmaf(p, w, 0.00573950773f);
    p = fmaf(p, w, -0.0076224613f);
    p = fmaf(p, w, 0.00943887047f);
    p = fmaf(p, w, 1.00167406f);
    p = fmaf(p, w, 2.83297682f);
  }
  return p * x;
}

__device__ inline float jax_normal_pt(uint32_t k0, uint32_t k1, uint32_t e) {
  uint32_t o0, o1;
  tf2x32(k0, k1, 0u, e, o0, o1);
  uint32_t bits = o0 ^ o1;
  float f = __uint_as_float((bits >> 9) | 0x3f800000u) - 1.0f;
  const float LO = -0.99999994f;
  float u = fmaxf(LO, fmaf(f, 2.0f, LO));
  return 1.41421356f * erfinv_f32(u);
}

struct OodArgs {
  const float* x;
  const float* noise_w;
  const float* noise_b;
  const float* feat_w[5];
  const float* feat_b[5];
  const float* mu_w[5];
  const float* mu_b[5];
  const float* std_w[5];
  const float* std_b[5];
  const float* clf_w;
  const float* clf_b;
  float* mean_out[5];
  float* std_out[5];
  float* out;      // (B,)
  float* gws;      // per (b,I) 560 floats: g[540] | rs[20]
  uint32_t fk0[5], fk1[5];
};

// Single padded image buffer: x is loaded padded, the noise conv is computed
// into registers, then xi overwrites the same buffer in place (borders stay
// zero).  Pitch 35 keeps phase-3 lane banks conflict-free (3*ss mod 32).
#define PITCH 35
#define CHSZ  (34 * PITCH)   // 1190
#define XSZ   (3 * CHSZ)     // 3570
#define A_NW   XSZ           // 81
#define A_NB   (XSZ + 81)    // 3
#define A_SMEM (XSZ + 84)    // 3654 floats = 14.6 KB

// ---------------------------------------------------------------------------
// KERNEL A: conv + g-reduction, g/rs blob to ws.
// 320 threads = 10 groups x 32 lanes; each lane owns one output row and TWO
// k-values (acc[2][9]) so every xi LDS read feeds 18 FMAs.  Live ~46 VGPRs.
// ---------------------------------------------------------------------------
template<int S, int STRIDE>
__device__ __forceinline__ void stageA(const OodArgs& A_, float* smem, int i) {
  constexpr int Wd = 32 / STRIDE;
  const int b = blockIdx.x;
  const int t = threadIdx.x;
  float* s_img = smem;
  float* s_nw  = smem + A_NW;
  float* s_nb  = smem + A_NB;

  // ---- phase 1: zero padded buffer, load x[b] interior, weights ----
  for (int p = t; p < XSZ; p += 320) s_img[p] = 0.0f;
  if (t < 81) s_nw[t] = A_.noise_w[81 * i + t];
  if (t < 3)  s_nb[t] = A_.noise_b[3 * i + t];
  __syncthreads();
  const float* xb = A_.x + (size_t)b * 3072;
  for (int p = t; p < 3072; p += 320) {
    int ci = p >> 10, rr = p & 1023, yy = rr >> 5, xx = rr & 31;
    s_img[ci * CHSZ + (yy + 1) * PITCH + (xx + 1)] = xb[p];
  }
  __syncthreads();

  // ---- phase 2: conv into regs (192 threads, 16-px runs), write xi in place
  float acc2[16];
  int ob = 0;
  const bool act = (t < 192);
  if (act) {
    const int co = t / 64, r = t % 64, y = r >> 1, xs = (r & 1) * 16;
    ob = co * CHSZ + (y + 1) * PITCH + (xs + 1);
    const float nb = s_nb[co];
    #pragma unroll
    for (int j = 0; j < 16; ++j) acc2[j] = nb;
    #pragma unroll
    for (int c2 = 0; c2 < 3; ++c2) {
      float nwr[9];
      #pragma unroll
      for (int q = 0; q < 9; ++q) nwr[q] = s_nw[co * 27 + c2 * 9 + q];
      const int wb = c2 * CHSZ + y * PITCH + xs;
      float P[3], Q[3], R[3];
      #pragma unroll
      for (int d = 0; d < 3; ++d) {
        P[d] = s_img[wb + d * PITCH];
        Q[d] = s_img[wb + d * PITCH + 1];
      }
#define CSTEP(J, P_, Q_, R_) { \
      _Pragma("unroll") \
      for (int d = 0; d < 3; ++d) R_[d] = s_img[wb + d * PITCH + (J) + 2]; \
      _Pragma("unroll") \
      for (int d = 0; d < 3; ++d) { \
        acc2[J] = fmaf(nwr[d*3+0], P_[d], acc2[J]); \
        acc2[J] = fmaf(nwr[d*3+1], Q_[d], acc2[J]); \
        acc2[J] = fmaf(nwr[d*3+2], R_[d], acc2[J]); \
      } }
      CSTEP(0,P,Q,R)  CSTEP(1,Q,R,P)  CSTEP(2,R,P,Q)
      CSTEP(3,P,Q,R)  CSTEP(4,Q,R,P)  CSTEP(5,R,P,Q)
      CSTEP(6,P,Q,R)  CSTEP(7,Q,R,P)  CSTEP(8,R,P,Q)
      CSTEP(9,P,Q,R)  CSTEP(10,Q,R,P) CSTEP(11,R,P,Q)
      CSTEP(12,P,Q,R) CSTEP(13,Q,R,P) CSTEP(14,R,P,Q)
      CSTEP(15,P,Q,R)
#undef CSTEP
    }
  }
  __syncthreads();                 // all conv reads done before any overwrite
  if (act) {
    #pragma unroll
    for (int j = 0; j < 16; ++j) {
      const float v = acc2[j] + s_img[ob + j];   // xi = conv + x
      s_img[ob + j] = v;
    }
  }
  __syncthreads();

  // ---- phase 3: g[wh][k][ci*9+q] = sum_s w[k,s]*xi[ci,patch(s,q)] ----
  const int g  = t >> 5;           // 0..9
  const int ss = t & 31;           // row / spatial sub
  const int wh = g & 1;
  const int k0 = (g >> 1) * 2;     // this lane handles k0 and k0+1
  const float* wbase = (wh ? A_.std_w[i] : A_.mu_w[i]) + k0 * S;
  float* gdst = A_.gws + (size_t)(b * 5 + i) * 560;

#define REDUCE_WRITE(ci_) { \
    _Pragma("unroll") \
    for (int j = 0; j < 9; ++j) { \
      float v0 = a0[j], v1 = a1[j]; \
      v0 += __shfl_xor(v0, 1, 64);  v1 += __shfl_xor(v1, 1, 64); \
      v0 += __shfl_xor(v0, 2, 64);  v1 += __shfl_xor(v1, 2, 64); \
      v0 += __shfl_xor(v0, 4, 64);  v1 += __shfl_xor(v1, 4, 64); \
      v0 += __shfl_xor(v0, 8, 64);  v1 += __shfl_xor(v1, 8, 64); \
      v0 += __shfl_xor(v0, 16, 64); v1 += __shfl_xor(v1, 16, 64); \
      a0[j] = v0; a1[j] = v1; \
    } \
    if ((ci_) == 0) { \
      rs0 += __shfl_xor(rs0, 1, 64); rs0 += __shfl_xor(rs0, 2, 64); \
      rs0 += __shfl_xor(rs0, 4, 64); rs0 += __shfl_xor(rs0, 8, 64); \
      rs0 += __shfl_xor(rs0, 16, 64); \
      rs1 += __shfl_xor(rs1, 1, 64); rs1 += __shfl_xor(rs1, 2, 64); \
      rs1 += __shfl_xor(rs1, 4, 64); rs1 += __shfl_xor(rs1, 8, 64); \
      rs1 += __shfl_xor(rs1, 16, 64); \
    } \
    if (ss == 0) { \
      _Pragma("unroll") \
      for (int j = 0; j < 9; ++j) { \
        gdst[(wh * 10 + k0) * 27 + (ci_) * 9 + j]     = a0[j]; \
        gdst[(wh * 10 + k0 + 1) * 27 + (ci_) * 9 + j] = a1[j]; \
      } \
      if ((ci_) == 0) { \
        gdst[540 + wh * 10 + k0]     = rs0; \
        gdst[540 + wh * 10 + k0 + 1] = rs1; \
      } \
    } }

  if constexpr (STRIDE == 1) {
    const float* wr = wbase + ss * 32;   // k0 row; k1 row at wr + S
    #pragma unroll
    for (int ci = 0; ci < 3; ++ci) {
      const int rb = ci * CHSZ + ss * PITCH;
      float a0[9], a1[9];
      #pragma unroll
      for (int j = 0; j < 9; ++j) { a0[j] = 0.0f; a1[j] = 0.0f; }
      float rs0 = 0.0f, rs1 = 0.0f;
      float Av[3], Bv[3], Cv[3];
      #pragma unroll
      for (int u = 0; u < 3; ++u) {
        Av[u] = s_img[rb + u * PITCH];
        Bv[u] = s_img[rb + u * PITCH + 1];
      }
#define WCOMP(V, L) ((L) == 0 ? (V).x : (L) == 1 ? (V).y : (L) == 2 ? (V).z : (V).w)
#define STEP(X, P_, Q_, R_, W0, W1) { \
    _Pragma("unroll") \
    for (int u = 0; u < 3; ++u) R_[u] = s_img[rb + u * PITCH + (X) + 2]; \
    const float w0c = WCOMP(W0, (X) & 3); \
    const float w1c = WCOMP(W1, (X) & 3); \
    _Pragma("unroll") \
    for (int dy = 0; dy < 3; ++dy) { \
      a0[dy*3+0] = fmaf(w0c, P_[dy], a0[dy*3+0]); a1[dy*3+0] = fmaf(w1c, P_[dy], a1[dy*3+0]); \
      a0[dy*3+1] = fmaf(w0c, Q_[dy], a0[dy*3+1]); a1[dy*3+1] = fmaf(w1c, Q_[dy], a1[dy*3+1]); \
      a0[dy*3+2] = fmaf(w0c, R_[dy], a0[dy*3+2]); a1[dy*3+2] = fmaf(w1c, R_[dy], a1[dy*3+2]); \
    } \
    if (ci == 0) { rs0 += w0c; rs1 += w1c; } }
#define G4_0(c) { const float4 w0 = *(const float4*)(wr + (c)); \
                  const float4 w1 = *(const float4*)(wr + S + (c)); \
    STEP((c)+0, Av, Bv, Cv, w0, w1) STEP((c)+1, Bv, Cv, Av, w0, w1) \
    STEP((c)+2, Cv, Av, Bv, w0, w1) STEP((c)+3, Av, Bv, Cv, w0, w1) }
#define G4_1(c) { const float4 w0 = *(const float4*)(wr + (c)); \
                  const float4 w1 = *(const float4*)(wr + S + (c)); \
    STEP((c)+0, Bv, Cv, Av, w0, w1) STEP((c)+1, Cv, Av, Bv, w0, w1) \
    STEP((c)+2, Av, Bv, Cv, w0, w1) STEP((c)+3, Bv, Cv, Av, w0, w1) }
#define G4_2(c) { const float4 w0 = *(const float4*)(wr + (c)); \
                  const float4 w1 = *(const float4*)(wr + S + (c)); \
    STEP((c)+0, Cv, Av, Bv, w0, w1) STEP((c)+1, Av, Bv, Cv, w0, w1) \
    STEP((c)+2, Bv, Cv, Av, w0, w1) STEP((c)+3, Cv, Av, Bv, w0, w1) }

      G4_0(0) G4_1(4) G4_2(8) G4_0(12) G4_1(16) G4_2(20) G4_0(24) G4_1(28)

#undef G4_0
#undef G4_1
#undef G4_2
#undef STEP
#undef WCOMP
      REDUCE_WRITE(ci)
    }
  } else {
    constexpr int PER = (S >= 32) ? (S / 32) : 1;   // 8 / 2 / 1
    #pragma unroll
    for (int ci = 0; ci < 3; ++ci) {
      float a0[9], a1[9];
      #pragma unroll
      for (int j = 0; j < 9; ++j) { a0[j] = 0.0f; a1[j] = 0.0f; }
      float rs0 = 0.0f, rs1 = 0.0f;
      if (S >= 32 || ss < S) {
        #pragma unroll
        for (int u = 0; u < PER; ++u) {
          const int s  = (S >= 32) ? (ss * PER + u) : ss;
          const int yo = s / Wd, xo = s % Wd;
          const float wx0 = wbase[s];
          const float wx1 = wbase[S + s];
          #pragma unroll
          for (int dy = 0; dy < 3; ++dy) {
            const int ba = ci * CHSZ + (yo * STRIDE + dy + 1) * PITCH + (xo * STRIDE + 1);
            #pragma unroll
            for (int dx = 0; dx < 3; ++dx) {
              const float v = s_img[ba + dx];
              a0[dy*3+dx] = fmaf(wx0, v, a0[dy*3+dx]);
              a1[dy*3+dx] = fmaf(wx1, v, a1[dy*3+dx]);
            }
          }
          if (ci == 0) { rs0 += wx0; rs1 += wx1; }
        }
      }
      REDUCE_WRITE(ci)
    }
  }
#undef REDUCE_WRITE
}

__global__ __launch_bounds__(320, 5)
void ood_a(OodArgs A_) {
  __shared__ float smem[A_SMEM];
  const int y = blockIdx.y;
  switch (y) {
    case 0:
    case 1: stageA<1024, 1>(A_, smem, y); break;
    case 2: stageA< 256, 2>(A_, smem, 2); break;
    case 3: stageA<  64, 4>(A_, smem, 3); break;
    default: stageA< 16, 8>(A_, smem, 4); break;
  }
}

// ---------------------------------------------------------------------------
// KERNEL B: one block per b; loops all 5 stages (std, mahal+RNG, argmax,
// outputs) and applies the classifier at the end (scores never leave LDS).
// ---------------------------------------------------------------------------
__global__ __launch_bounds__(320)
void ood_b(OodArgs A_) {
  __shared__ float smem[5696];
  float* s_g   = smem;            // 540
  float* s_rs  = smem + 540;      // 20
  float* s_std = smem + 560;      // up to 5120
  float* s_pt  = smem + 5680;     // 10
  float* s_sc  = smem + 5690;     // 5
  int*   s_idx = (int*)(smem + 5695);
  const int b = blockIdx.x;
  const int t = threadIdx.x;

  #pragma unroll 1
  for (int i = 0; i < 5; ++i) {
    const int C   = (i < 2) ? 64 : (i == 2 ? 128 : (i == 3 ? 256 : 512));
    const int csh = (i < 2) ? 6  : (i == 2 ? 7   : (i == 3 ? 8   : 9));
    const float* feat_w = A_.feat_w[i];
    const float* feat_b = A_.feat_b[i];
    const float* gsrc = A_.gws + (size_t)(b * 5 + i) * 560;
    __syncthreads();                        // previous iter done with smem
    for (int p = t; p < 560; p += 320) smem[p] = gsrc[p];
    __syncthreads();

    // 4a: s_std[k*C+c]
    for (int v = t; v < 10 * C; v += 320) {
      const int k2 = v >> csh, c = v & (C - 1);
      const float* fw = feat_w + c * 27;
      float a2 = 0.0f;
      #pragma unroll
      for (int j = 0; j < 27; ++j) a2 = fmaf(s_g[(10 + k2) * 27 + j], fw[j], a2);
      a2 = fmaf(feat_b[c], s_rs[10 + k2], a2) + A_.std_b[i][k2];
      s_std[v] = a2;
    }
    __syncthreads();

    // 4b: mahal — wave g handles classes {g, g+5}
    {
      const int g = t >> 6, ln = t & 63;
      const uint32_t fk0 = A_.fk0[i], fk1 = A_.fk1[i];
      float m0 = 0.0f, m1 = 0.0f;
      for (int c = ln; c < C; c += 64) {
        const float sd0 = s_std[g * C + c];
        const float e0  = jax_normal_pt(fk0, fk1, (uint32_t)((b * 10 + g) * C + c));
        m0 = fmaf(sd0 * sd0, e0 * e0, m0);
        const float sd1 = s_std[(g + 5) * C + c];
        const float e1  = jax_normal_pt(fk0, fk1, (uint32_t)((b * 10 + g + 5) * C + c));
        m1 = fmaf(sd1 * sd1, e1 * e1, m1);
      }
      #pragma unroll
      for (int off = 32; off > 0; off >>= 1) {
        m0 += __shfl_down(m0, off, 64);
        m1 += __shfl_down(m1, off, 64);
      }
      if (ln == 0) { s_pt[g] = m0; s_pt[g + 5] = m1; }
    }
    __syncthreads();
    if (t == 0) {
      float best = -INFINITY; int bi = 0;
      #pragma unroll
      for (int k = 0; k < 10; ++k) {
        float m = -0.5f * s_pt[k];
        if (m > best) { best = m; bi = k; }
      }
      s_sc[i] = best; *s_idx = bi;
    }
    __syncthreads();

    // 5: outputs (mean recomputed for argmax class; std from LDS)
    const int idx = *s_idx;
    float* mo = A_.mean_out[i];
    float* so = A_.std_out[i];
    const float mb   = A_.mu_b[i][idx];
    const float rs0v = s_rs[idx];
    for (int c = t; c < C; c += 320) {
      const float* fw = feat_w + c * 27;
      float a1v = 0.0f;
      #pragma unroll
      for (int j = 0; j < 27; ++j) a1v = fmaf(s_g[idx * 27 + j], fw[j], a1v);
      a1v = fmaf(feat_b[c], rs0v, a1v) + mb;
      mo[(size_t)b * C + c] = a1v;
      so[(size_t)b * C + c] = s_std[idx * C + c];
    }
  }
  __syncthreads();
  if (t == 0) {
    float acc = A_.clf_b[0];
    #pragma unroll
    for (int i2 = 0; i2 < 5; ++i2) acc = fmaf(s_sc[i2], A_.clf_w[i2], acc);
    A_.out[b] = acc;
  }
}

extern "C" void kernel_launch(void* const* d_in, const int* in_sizes, int n_in,
                              void* d_out, int out_size, void* d_ws, size_t ws_size,
                              hipStream_t stream) {
  (void)in_sizes; (void)n_in; (void)out_size; (void)ws_size;
  float* out = (float*)d_out;
  float* ws  = (float*)d_ws;

  OodArgs A_;
  A_.x       = (const float*)d_in[0];
  A_.noise_w = (const float*)d_in[1];
  A_.noise_b = (const float*)d_in[2];
  A_.clf_w   = (const float*)d_in[33];
  A_.clf_b   = (const float*)d_in[34];
  const size_t NMEAN = 1048576;
  const size_t moff[5] = {1024, 66560, 132096, 263168, 525312};
  for (int i = 0; i < 5; ++i) {
    A_.feat_w[i]   = (const float*)d_in[3 + 6 * i];
    A_.feat_b[i]   = (const float*)d_in[4 + 6 * i];
    A_.mu_w[i]     = (const float*)d_in[5 + 6 * i];
    A_.mu_b[i]     = (const float*)d_in[6 + 6 * i];
    A_.std_w[i]    = (const float*)d_in[7 + 6 * i];
    A_.std_b[i]    = (const float*)d_in[8 + 6 * i];
    A_.mean_out[i] = out + moff[i];
    A_.std_out[i]  = out + moff[i] + NMEAN;
    tf2x32(0u, 42u, 0u, (uint32_t)i, A_.fk0[i], A_.fk1[i]);
  }
  A_.out = out;
  A_.gws = ws;

  ood_a<<<dim3(B_SZ, 5), 320, 0, stream>>>(A_);
  ood_b<<<B_SZ, 320, 0, stream>>>(A_);
}